// Round 1
// baseline (1559.126 us; speedup 1.0000x reference)
//
#include <hip/hip_runtime.h>
#include <hip/hip_bf16.h>

// Problem constants: B=4, C=512, H=W=64 -> N=4096, CK=64
#define NB 4
#define CC 512
#define NN 4096
#define CKK 64

// ---------------------------------------------------------------------------
// K1: projections. Y[o][n] = sum_c W[o][c] * x[b][c][n] + bias[o]
// Virtual 640 output rows: tile 0 -> f (Wf), tile 1 -> g (Wg), tiles 2..9 -> h (Wh)
// 64x64 tile, 256 threads, 4x4 per-thread micro-tile, K-chunk 16.
// ---------------------------------------------------------------------------
__launch_bounds__(256)
__global__ void proj_gemm(const float* __restrict__ x,
                          const float* __restrict__ Wf, const float* __restrict__ bf_,
                          const float* __restrict__ Wg, const float* __restrict__ bg_,
                          const float* __restrict__ Wh, const float* __restrict__ bh_,
                          float* __restrict__ F, float* __restrict__ G,
                          float* __restrict__ Hx) {
    const int N = NN, C = CC;
    int n0 = blockIdx.x * 64;
    int to = blockIdx.y;
    int b  = blockIdx.z;
    const float* W; const float* bias; float* Y;
    if (to == 0)      { W = Wf; bias = bf_; Y = F + (size_t)b * CKK * N; }
    else if (to == 1) { W = Wg; bias = bg_; Y = G + (size_t)b * CKK * N; }
    else {
        int r0 = (to - 2) * 64;
        W = Wh + (size_t)r0 * C; bias = bh_ + r0;
        Y = Hx + (size_t)b * CC * N + (size_t)r0 * N;
    }
    const float* xb = x + (size_t)b * C * N;

    __shared__ float Ws_[16][68];  // [c][o]  (stride 68 floats = 16B aligned rows)
    __shared__ float Xs[16][68];   // [c][n]
    int tid = threadIdx.x;
    int tx = tid & 15, ty = tid >> 4;
    float acc[4][4] = {};

    for (int kc = 0; kc < C; kc += 16) {
        {   // load W chunk [64 o][16 c] -> Ws_[c][o]
            int c = tid & 15, o = tid >> 4;
            #pragma unroll
            for (int r = 0; r < 4; r++)
                Ws_[c][o + 16 * r] = W[(size_t)(o + 16 * r) * C + kc + c];
        }
        {   // load x chunk [16 c][64 n] -> Xs[c][n]
            int n = tid & 63, c4 = tid >> 6;
            #pragma unroll
            for (int r = 0; r < 4; r++)
                Xs[c4 + 4 * r][n] = xb[(size_t)(kc + c4 + 4 * r) * N + n0 + n];
        }
        __syncthreads();
        #pragma unroll
        for (int k = 0; k < 16; k++) {
            float a[4], bv[4];
            #pragma unroll
            for (int i = 0; i < 4; i++) a[i] = Ws_[k][ty * 4 + i];
            #pragma unroll
            for (int j = 0; j < 4; j++) bv[j] = Xs[k][tx * 4 + j];
            #pragma unroll
            for (int i = 0; i < 4; i++)
                #pragma unroll
                for (int j = 0; j < 4; j++)
                    acc[i][j] += a[i] * bv[j];
        }
        __syncthreads();
    }
    #pragma unroll
    for (int i = 0; i < 4; i++) {
        int o = ty * 4 + i;
        float bb = bias[o];
        float4 v;
        v.x = acc[i][0] + bb; v.y = acc[i][1] + bb;
        v.z = acc[i][2] + bb; v.w = acc[i][3] + bb;
        *(float4*)(Y + (size_t)o * N + n0 + tx * 4) = v;
    }
}

// ---------------------------------------------------------------------------
// K2: energy chunk. E[i_local][j] = sum_k F[k][r0+i]*G[k][j], K=64.
// F,G already offset to batch b. 64x64 tiles.
// ---------------------------------------------------------------------------
__launch_bounds__(256)
__global__ void energy_gemm(const float* __restrict__ F, const float* __restrict__ G,
                            float* __restrict__ E, int r0) {
    const int N = NN;
    int j0 = blockIdx.x * 64;
    int i0 = blockIdx.y * 64;  // local within chunk
    __shared__ float Fs[16][68];  // [k][i]
    __shared__ float Gs[16][68];  // [k][j]
    int tid = threadIdx.x;
    int tx = tid & 15, ty = tid >> 4;
    int t = tid & 63, k4 = tid >> 6;
    float acc[4][4] = {};
    for (int kc = 0; kc < CKK; kc += 16) {
        #pragma unroll
        for (int r = 0; r < 4; r++) {
            Fs[k4 + 4 * r][t] = F[(size_t)(kc + k4 + 4 * r) * N + r0 + i0 + t];
            Gs[k4 + 4 * r][t] = G[(size_t)(kc + k4 + 4 * r) * N + j0 + t];
        }
        __syncthreads();
        #pragma unroll
        for (int k = 0; k < 16; k++) {
            float a[4], bv[4];
            #pragma unroll
            for (int i = 0; i < 4; i++) a[i] = Fs[k][ty * 4 + i];
            #pragma unroll
            for (int j = 0; j < 4; j++) bv[j] = Gs[k][tx * 4 + j];
            #pragma unroll
            for (int i = 0; i < 4; i++)
                #pragma unroll
                for (int j = 0; j < 4; j++)
                    acc[i][j] += a[i] * bv[j];
        }
        __syncthreads();
    }
    #pragma unroll
    for (int i = 0; i < 4; i++) {
        float4 v;
        v.x = acc[i][0]; v.y = acc[i][1]; v.z = acc[i][2]; v.w = acc[i][3];
        *(float4*)(E + (size_t)(i0 + ty * 4 + i) * N + j0 + tx * 4) = v;
    }
}

// ---------------------------------------------------------------------------
// K3: row softmax in place. One block (256 thr) per row of 4096.
// ---------------------------------------------------------------------------
__launch_bounds__(256)
__global__ void softmax_rows(float* __restrict__ P) {
    const int N = NN;
    float* p = P + (size_t)blockIdx.x * N;
    int tid = threadIdx.x;
    float v[16];
    float m = -1e30f;
    #pragma unroll
    for (int r = 0; r < 16; r++) { v[r] = p[tid + 256 * r]; m = fmaxf(m, v[r]); }
    #pragma unroll
    for (int off = 32; off > 0; off >>= 1) m = fmaxf(m, __shfl_down(m, off));
    __shared__ float redm[4];
    __shared__ float reds[4];
    int wave = tid >> 6, lane = tid & 63;
    if (lane == 0) redm[wave] = m;
    __syncthreads();
    m = fmaxf(fmaxf(redm[0], redm[1]), fmaxf(redm[2], redm[3]));
    float s = 0.f;
    #pragma unroll
    for (int r = 0; r < 16; r++) { v[r] = __expf(v[r] - m); s += v[r]; }
    #pragma unroll
    for (int off = 32; off > 0; off >>= 1) s += __shfl_down(s, off);
    if (lane == 0) reds[wave] = s;
    __syncthreads();
    s = reds[0] + reds[1] + reds[2] + reds[3];
    float inv = 1.0f / s;
    #pragma unroll
    for (int r = 0; r < 16; r++) p[tid + 256 * r] = v[r] * inv;
}

// ---------------------------------------------------------------------------
// K4: O[c][r0+i] = sum_j Hx[c][j] * P[i][j]; out = gamma*O + x (fused epilogue)
// Hx, x, out already offset to batch b. P rows are chunk-local.
// ---------------------------------------------------------------------------
__launch_bounds__(256)
__global__ void out_gemm(const float* __restrict__ Hx, const float* __restrict__ P,
                         const float* __restrict__ xb, const float* __restrict__ gamma,
                         float* __restrict__ out, int r0) {
    const int N = NN;
    int i0 = blockIdx.x * 64;  // local within chunk
    int c0 = blockIdx.y * 64;
    __shared__ float Hs[16][68];  // [j][c]
    __shared__ float Ps[16][68];  // [j][i]
    int tid = threadIdx.x;
    int tx = tid & 15, ty = tid >> 4;
    int jl = tid & 15, rl = tid >> 4;
    float acc[4][4] = {};
    for (int jc = 0; jc < N; jc += 16) {
        #pragma unroll
        for (int r = 0; r < 4; r++) {
            Hs[jl][rl + 16 * r] = Hx[(size_t)(c0 + rl + 16 * r) * N + jc + jl];
            Ps[jl][rl + 16 * r] = P[(size_t)(i0 + rl + 16 * r) * N + jc + jl];
        }
        __syncthreads();
        #pragma unroll
        for (int k = 0; k < 16; k++) {
            float a[4], bv[4];
            #pragma unroll
            for (int i = 0; i < 4; i++) a[i] = Hs[k][ty * 4 + i];
            #pragma unroll
            for (int j = 0; j < 4; j++) bv[j] = Ps[k][tx * 4 + j];
            #pragma unroll
            for (int i = 0; i < 4; i++)
                #pragma unroll
                for (int j = 0; j < 4; j++)
                    acc[i][j] += a[i] * bv[j];
        }
        __syncthreads();
    }
    float gv = gamma[0];
    int ig = r0 + i0 + tx * 4;  // global pixel column
    #pragma unroll
    for (int i = 0; i < 4; i++) {
        int c = c0 + ty * 4 + i;
        const float4 xv = *(const float4*)(xb + (size_t)c * N + ig);
        float4 ov;
        ov.x = gv * acc[i][0] + xv.x;
        ov.y = gv * acc[i][1] + xv.y;
        ov.z = gv * acc[i][2] + xv.z;
        ov.w = gv * acc[i][3] + xv.w;
        *(float4*)(out + (size_t)c * N + ig) = ov;
    }
}

extern "C" void kernel_launch(void* const* d_in, const int* in_sizes, int n_in,
                              void* d_out, int out_size, void* d_ws, size_t ws_size,
                              hipStream_t stream) {
    const float* x     = (const float*)d_in[0];
    const float* Wf    = (const float*)d_in[1];
    const float* bf    = (const float*)d_in[2];
    const float* Wg    = (const float*)d_in[3];
    const float* bg    = (const float*)d_in[4];
    const float* Wh    = (const float*)d_in[5];
    const float* bh    = (const float*)d_in[6];
    const float* gamma = (const float*)d_in[7];
    float* out = (float*)d_out;
    float* ws  = (float*)d_ws;

    const int B = NB, C = CC, N = NN, CK = CKK;

    // Workspace layout (floats):
    //   F  [B][CK][N]   1,048,576
    //   G  [B][CK][N]   1,048,576
    //   Hx [B][C][N]    8,388,608
    //   P  [RCH][N]     attention chunk (auto-sized from ws_size)
    float* F  = ws;
    float* G  = F + (size_t)B * CK * N;
    float* Hx = G + (size_t)B * CK * N;
    float* P  = Hx + (size_t)B * C * N;
    size_t base_floats = (size_t)B * CK * N * 2 + (size_t)B * C * N;  // 10,485,760
    size_t avail = (ws_size / 4 > base_floats) ? (ws_size / 4 - base_floats) : 0;
    int RCH = (int)((avail / (size_t)N) / 64) * 64;
    if (RCH > N) RCH = N;
    if (RCH < 64) RCH = 64;  // minimum viable chunk

    // K1: all three projections
    proj_gemm<<<dim3(N / 64, 10, B), dim3(256), 0, stream>>>(
        x, Wf, bf, Wg, bg, Wh, bh, F, G, Hx);

    // K2-K4 per batch, per query-row chunk
    for (int b = 0; b < B; b++) {
        const float* Fb = F + (size_t)b * CK * N;
        const float* Gb = G + (size_t)b * CK * N;
        const float* Hb = Hx + (size_t)b * C * N;
        const float* xb = x + (size_t)b * C * N;
        float* ob = out + (size_t)b * C * N;
        for (int r0 = 0; r0 < N; r0 += RCH) {
            int rows = (RCH < N - r0) ? RCH : (N - r0);
            energy_gemm<<<dim3(N / 64, rows / 64), dim3(256), 0, stream>>>(Fb, Gb, P, r0);
            softmax_rows<<<dim3(rows), dim3(256), 0, stream>>>(P);
            out_gemm<<<dim3(rows / 64, C / 64), dim3(256), 0, stream>>>(Hb, P, xb, gamma, ob, r0);
        }
    }
}

// Round 2
// 389.710 us; speedup vs baseline: 4.0007x; 4.0007x over previous
//
#include <hip/hip_runtime.h>
#include <hip/hip_bf16.h>

// Problem constants: B=4, C=512, H=W=64 -> N=4096, CK=64
#define NB 4
#define CC 512
#define NN 4096
#define CKK 64

typedef _Float16 f16x4 __attribute__((ext_vector_type(4)));
typedef _Float16 f16x8 __attribute__((ext_vector_type(8)));
typedef float    f32x4 __attribute__((ext_vector_type(4)));

// ---------------------------------------------------------------------------
// async global->LDS, 16 B per lane. LDS dest is wave-uniform base + lane*16.
// ---------------------------------------------------------------------------
__device__ __forceinline__ void g2l16(const _Float16* g, _Float16* l) {
    __builtin_amdgcn_global_load_lds(
        (const __attribute__((address_space(1))) void*)g,
        (__attribute__((address_space(3))) void*)l, 16, 0, 0);
}

// Stage a 128-row x 32-col f16 tile (row stride ldg) into LDS [128][32] unpadded.
// 8 chunks of 16 rows; wave w covers chunks w and w+4; lane l -> row l>>2, seg l&3.
__device__ __forceinline__ void stage_tile(const _Float16* __restrict__ g, int ldg,
                                           _Float16* lds, int lane, int wave) {
    #pragma unroll
    for (int r = 0; r < 2; r++) {
        int q = r * 4 + wave;
        int row = q * 16 + (lane >> 2);
        int col = (lane & 3) * 8;
        g2l16(g + (size_t)row * ldg + col, lds + q * 512 + lane * 8);
    }
}

// ---------------------------------------------------------------------------
// K1: projections (fp32 compute, f16 outputs).
// tile 0 -> F_t [N][64] (transposed), tile 1 -> G_t [N][64] (transposed),
// tiles 2..9 -> Hx [C][N].
// ---------------------------------------------------------------------------
__launch_bounds__(256)
__global__ void proj_gemm(const float* __restrict__ x,
                          const float* __restrict__ Wf, const float* __restrict__ bf_,
                          const float* __restrict__ Wg, const float* __restrict__ bg_,
                          const float* __restrict__ Wh, const float* __restrict__ bh_,
                          _Float16* __restrict__ Ft, _Float16* __restrict__ Gt,
                          _Float16* __restrict__ Hx) {
    const int N = NN, C = CC;
    int n0 = blockIdx.x * 64;
    int to = blockIdx.y;
    int b  = blockIdx.z;
    const float* W; const float* bias;
    if (to == 0)      { W = Wf; bias = bf_; }
    else if (to == 1) { W = Wg; bias = bg_; }
    else {
        int r0 = (to - 2) * 64;
        W = Wh + (size_t)r0 * C; bias = bh_ + r0;
    }
    const float* xb = x + (size_t)b * C * N;

    __shared__ float Ws_[16][68];
    __shared__ float Xs[16][68];
    int tid = threadIdx.x;
    int tx = tid & 15, ty = tid >> 4;
    float acc[4][4] = {};

    for (int kc = 0; kc < C; kc += 16) {
        {
            int c = tid & 15, o = tid >> 4;
            #pragma unroll
            for (int r = 0; r < 4; r++)
                Ws_[c][o + 16 * r] = W[(size_t)(o + 16 * r) * C + kc + c];
        }
        {
            int n = tid & 63, c4 = tid >> 6;
            #pragma unroll
            for (int r = 0; r < 4; r++)
                Xs[c4 + 4 * r][n] = xb[(size_t)(kc + c4 + 4 * r) * N + n0 + n];
        }
        __syncthreads();
        #pragma unroll
        for (int k = 0; k < 16; k++) {
            float a[4], bv[4];
            #pragma unroll
            for (int i = 0; i < 4; i++) a[i] = Ws_[k][ty * 4 + i];
            #pragma unroll
            for (int j = 0; j < 4; j++) bv[j] = Xs[k][tx * 4 + j];
            #pragma unroll
            for (int i = 0; i < 4; i++)
                #pragma unroll
                for (int j = 0; j < 4; j++)
                    acc[i][j] += a[i] * bv[j];
        }
        __syncthreads();
    }
    float bb[4];
    #pragma unroll
    for (int i = 0; i < 4; i++) bb[i] = bias[ty * 4 + i];

    if (to <= 1) {
        // transposed store: Yt[n][o], 64-wide rows
        _Float16* Yt = (to == 0 ? Ft : Gt) + (size_t)b * NN * CKK;
        #pragma unroll
        for (int j = 0; j < 4; j++) {
            f16x4 v = { (_Float16)(acc[0][j] + bb[0]), (_Float16)(acc[1][j] + bb[1]),
                        (_Float16)(acc[2][j] + bb[2]), (_Float16)(acc[3][j] + bb[3]) };
            *(f16x4*)(Yt + (size_t)(n0 + tx * 4 + j) * CKK + ty * 4) = v;
        }
    } else {
        _Float16* Y = Hx + (size_t)b * CC * N + (size_t)(to - 2) * 64 * N;
        #pragma unroll
        for (int i = 0; i < 4; i++) {
            f16x4 v = { (_Float16)(acc[i][0] + bb[i]), (_Float16)(acc[i][1] + bb[i]),
                        (_Float16)(acc[i][2] + bb[i]), (_Float16)(acc[i][3] + bb[i]) };
            *(f16x4*)(Y + (size_t)(ty * 4 + i) * N + n0 + tx * 4) = v;
        }
    }
}

// ---------------------------------------------------------------------------
// K2: energy MFMA. E[i][j] = sum_k Ft[i][k] * Gt[j][k]  (NT, K=64)
// 128x128 tile, 4 waves in 2x2, 4x4 16x16x32 MFMA fragments per wave.
// ---------------------------------------------------------------------------
__launch_bounds__(256)
__global__ void energy_mfma(const _Float16* __restrict__ Ft, const _Float16* __restrict__ Gt,
                            _Float16* __restrict__ E, int r0, int Rstr) {
    const int N = NN;
    int b = blockIdx.z;
    const _Float16* Arow = Ft + (size_t)b * N * CKK + (size_t)(r0 + blockIdx.y * 128) * CKK;
    const _Float16* Brow = Gt + (size_t)b * N * CKK + (size_t)(blockIdx.x * 128) * CKK;
    _Float16* Eb = E + (size_t)b * Rstr * N + (size_t)blockIdx.y * 128 * N + blockIdx.x * 128;
    __shared__ _Float16 As[128 * 32];
    __shared__ _Float16 Bs[128 * 32];
    int tid = threadIdx.x, lane = tid & 63, wave = tid >> 6;
    int wm = wave & 1, wn = wave >> 1, lrow = lane & 15, quad = lane >> 4;
    f32x4 acc[4][4] = {};
    #pragma unroll
    for (int kc = 0; kc < CKK; kc += 32) {
        __syncthreads();
        stage_tile(Arow + kc, CKK, As, lane, wave);
        stage_tile(Brow + kc, CKK, Bs, lane, wave);
        __syncthreads();
        f16x8 af[4], bf[4];
        #pragma unroll
        for (int mi = 0; mi < 4; mi++)
            af[mi] = *(const f16x8*)(As + (wm * 64 + mi * 16 + lrow) * 32 + quad * 8);
        #pragma unroll
        for (int ni = 0; ni < 4; ni++)
            bf[ni] = *(const f16x8*)(Bs + (wn * 64 + ni * 16 + lrow) * 32 + quad * 8);
        #pragma unroll
        for (int mi = 0; mi < 4; mi++)
            #pragma unroll
            for (int ni = 0; ni < 4; ni++)
                acc[mi][ni] = __builtin_amdgcn_mfma_f32_16x16x32_f16(af[mi], bf[ni], acc[mi][ni], 0, 0, 0);
    }
    #pragma unroll
    for (int mi = 0; mi < 4; mi++)
        #pragma unroll
        for (int ni = 0; ni < 4; ni++)
            #pragma unroll
            for (int r = 0; r < 4; r++) {
                int il = wm * 64 + mi * 16 + quad * 4 + r;
                int j  = wn * 64 + ni * 16 + lrow;
                Eb[(size_t)il * N + j] = (_Float16)acc[mi][ni][r];
            }
}

// ---------------------------------------------------------------------------
// K3: in-place f16 row softmax, one block per row.
// ---------------------------------------------------------------------------
__launch_bounds__(256)
__global__ void softmax_f16(_Float16* __restrict__ E, size_t bstride) {
    _Float16* p = E + blockIdx.y * bstride + (size_t)blockIdx.x * NN;
    int tid = threadIdx.x;
    f16x8 v0 = *(const f16x8*)(p + tid * 8);
    f16x8 v1 = *(const f16x8*)(p + 2048 + tid * 8);
    float f[16];
    #pragma unroll
    for (int j = 0; j < 8; j++) { f[j] = (float)v0[j]; f[8 + j] = (float)v1[j]; }
    float m = -1e30f;
    #pragma unroll
    for (int j = 0; j < 16; j++) m = fmaxf(m, f[j]);
    #pragma unroll
    for (int off = 32; off > 0; off >>= 1) m = fmaxf(m, __shfl_down(m, off));
    __shared__ float red[8];
    int wave = tid >> 6, lane = tid & 63;
    if (lane == 0) red[wave] = m;
    __syncthreads();
    m = fmaxf(fmaxf(red[0], red[1]), fmaxf(red[2], red[3]));
    float s = 0.f;
    #pragma unroll
    for (int j = 0; j < 16; j++) { f[j] = __expf(f[j] - m); s += f[j]; }
    #pragma unroll
    for (int off = 32; off > 0; off >>= 1) s += __shfl_down(s, off);
    if (lane == 0) red[4 + wave] = s;
    __syncthreads();
    s = red[4] + red[5] + red[6] + red[7];
    float inv = 1.0f / s;
    #pragma unroll
    for (int j = 0; j < 8; j++) { v0[j] = (_Float16)(f[j] * inv); v1[j] = (_Float16)(f[8 + j] * inv); }
    *(f16x8*)(p + tid * 8) = v0;
    *(f16x8*)(p + 2048 + tid * 8) = v1;
}

// ---------------------------------------------------------------------------
// K4: out MFMA. O[c][i] = sum_j Hx[c][j] * P[i][j]  (NT, K=4096)
// epilogue: out = gamma*O + x (fp32)
// ---------------------------------------------------------------------------
__launch_bounds__(256)
__global__ void out_mfma(const _Float16* __restrict__ Hx, const _Float16* __restrict__ P,
                         const float* __restrict__ x, const float* __restrict__ gamma,
                         float* __restrict__ out, int r0, int Rstr) {
    const int N = NN, C = CC;
    int b = blockIdx.z;
    int i0l = blockIdx.x * 128;
    int c0  = blockIdx.y * 128;
    const _Float16* Arow = Hx + (size_t)b * C * N + (size_t)c0 * N;
    const _Float16* Brow = P  + (size_t)b * Rstr * N + (size_t)i0l * N;
    __shared__ _Float16 As[128 * 32];
    __shared__ _Float16 Bs[128 * 32];
    int tid = threadIdx.x, lane = tid & 63, wave = tid >> 6;
    int wm = wave & 1, wn = wave >> 1, lrow = lane & 15, quad = lane >> 4;
    f32x4 acc[4][4] = {};
    for (int kc = 0; kc < N; kc += 32) {
        __syncthreads();
        stage_tile(Arow + kc, N, As, lane, wave);
        stage_tile(Brow + kc, N, Bs, lane, wave);
        __syncthreads();
        f16x8 af[4], bf[4];
        #pragma unroll
        for (int mi = 0; mi < 4; mi++)
            af[mi] = *(const f16x8*)(As + (wm * 64 + mi * 16 + lrow) * 32 + quad * 8);
        #pragma unroll
        for (int ni = 0; ni < 4; ni++)
            bf[ni] = *(const f16x8*)(Bs + (wn * 64 + ni * 16 + lrow) * 32 + quad * 8);
        #pragma unroll
        for (int mi = 0; mi < 4; mi++)
            #pragma unroll
            for (int ni = 0; ni < 4; ni++)
                acc[mi][ni] = __builtin_amdgcn_mfma_f32_16x16x32_f16(af[mi], bf[ni], acc[mi][ni], 0, 0, 0);
    }
    float gv = gamma[0];
    const float* xb = x + (size_t)b * C * N;
    float* ob = out + (size_t)b * C * N;
    int ig0 = r0 + i0l;
    #pragma unroll
    for (int mi = 0; mi < 4; mi++)
        #pragma unroll
        for (int ni = 0; ni < 4; ni++)
            #pragma unroll
            for (int r = 0; r < 4; r++) {
                int c = c0 + wm * 64 + mi * 16 + quad * 4 + r;
                int i = ig0 + wn * 64 + ni * 16 + lrow;
                ob[(size_t)c * N + i] = gv * acc[mi][ni][r] + xb[(size_t)c * N + i];
            }
}

extern "C" void kernel_launch(void* const* d_in, const int* in_sizes, int n_in,
                              void* d_out, int out_size, void* d_ws, size_t ws_size,
                              hipStream_t stream) {
    const float* x     = (const float*)d_in[0];
    const float* Wf    = (const float*)d_in[1];
    const float* bf    = (const float*)d_in[2];
    const float* Wg    = (const float*)d_in[3];
    const float* bg    = (const float*)d_in[4];
    const float* Wh    = (const float*)d_in[5];
    const float* bh    = (const float*)d_in[6];
    const float* gamma = (const float*)d_in[7];
    float* out = (float*)d_out;

    const int B = NB, C = CC, N = NN;

    // Workspace layout (bytes):
    //   Ft [B][N][64] f16   2 MiB
    //   Gt [B][N][64] f16   2 MiB
    //   Hx [B][C][N]  f16  16 MiB
    //   E  [B][R][N]  f16   chunk, auto-sized (134 MiB at R=4096)
    char* wsb = (char*)d_ws;
    _Float16* Ft = (_Float16*)wsb;
    _Float16* Gt = (_Float16*)(wsb + ((size_t)2 << 20));
    _Float16* Hx = (_Float16*)(wsb + ((size_t)4 << 20));
    _Float16* E  = (_Float16*)(wsb + ((size_t)20 << 20));
    size_t base = (size_t)20 << 20;
    size_t avail = (ws_size > base) ? ws_size - base : 0;
    size_t bytesPer128 = (size_t)B * N * 2 * 128;  // 4 MiB per 128 rows
    int R = (int)(avail / bytesPer128) * 128;
    if (R > N) R = N;
    if (R < 128) R = 128;

    proj_gemm<<<dim3(N / 64, 10, B), dim3(256), 0, stream>>>(
        x, Wf, bf, Wg, bg, Wh, bh, Ft, Gt, Hx);

    for (int r0 = 0; r0 < N; r0 += R) {
        int rows = (R < N - r0) ? R : (N - r0);
        energy_mfma<<<dim3(N / 128, rows / 128, B), dim3(256), 0, stream>>>(Ft, Gt, E, r0, R);
        softmax_f16<<<dim3(rows, B), dim3(256), 0, stream>>>(E, (size_t)R * N);
        out_mfma<<<dim3(rows / 128, C / 128, B), dim3(256), 0, stream>>>(Hx, E, x, gamma, out, r0, R);
    }
}

// Round 3
// 288.847 us; speedup vs baseline: 5.3978x; 1.3492x over previous
//
#include <hip/hip_runtime.h>
#include <hip/hip_bf16.h>

// Problem constants: B=4, C=512, H=W=64 -> N=4096, CK=64
#define NB 4
#define CC 512
#define NN 4096
#define CKK 64

typedef _Float16 f16x4 __attribute__((ext_vector_type(4)));
typedef _Float16 f16x8 __attribute__((ext_vector_type(8)));
typedef float    f32x4 __attribute__((ext_vector_type(4)));

// ---------------------------------------------------------------------------
// async global->LDS, 16 B per lane. LDS dest is wave-uniform base + lane*16.
// ---------------------------------------------------------------------------
__device__ __forceinline__ void g2l16(const _Float16* g, _Float16* l) {
    __builtin_amdgcn_global_load_lds(
        (const __attribute__((address_space(1))) void*)g,
        (__attribute__((address_space(3))) void*)l, 16, 0, 0);
}

// Stage a 128-row x 32-col f16 tile (row stride ldg) into LDS [128][32] unpadded.
__device__ __forceinline__ void stage_tile(const _Float16* __restrict__ g, int ldg,
                                           _Float16* lds, int lane, int wave) {
    #pragma unroll
    for (int r = 0; r < 2; r++) {
        int q = r * 4 + wave;
        int row = q * 16 + (lane >> 2);
        int col = (lane & 3) * 8;
        g2l16(g + (size_t)row * ldg + col, lds + q * 512 + lane * 8);
    }
}

// ---------------------------------------------------------------------------
// K0: pack Wf/Wg/Wh -> Wall[640][512] f16, biases -> Ball[640] fp32.
// ---------------------------------------------------------------------------
__launch_bounds__(256)
__global__ void convert_w(const float* __restrict__ Wf, const float* __restrict__ bf_,
                          const float* __restrict__ Wg, const float* __restrict__ bg_,
                          const float* __restrict__ Wh, const float* __restrict__ bh_,
                          _Float16* __restrict__ Wall, float* __restrict__ Ball) {
    int o = blockIdx.x;   // 0..639
    int t = threadIdx.x;  // 256
    const float* src;
    if (o < 64)       src = Wf + (size_t)o * CC;
    else if (o < 128) src = Wg + (size_t)(o - 64) * CC;
    else              src = Wh + (size_t)(o - 128) * CC;
    Wall[(size_t)o * CC + t]       = (_Float16)src[t];
    Wall[(size_t)o * CC + 256 + t] = (_Float16)src[256 + t];
    if (t == 0)
        Ball[o] = (o < 64) ? bf_[o] : (o < 128 ? bg_[o - 64] : bh_[o - 128]);
}

// ---------------------------------------------------------------------------
// K1: projections via MFMA. Y[o][n] = sum_c Wall[o][c]*x[c][n] + Ball[o]
// A = Wall (K-contig, async staged). B = x fp32, VGPR-converted into LDS[k][128].
// Outputs routed: o<64 -> Ft[n][64], o<128 -> Gt[n][64], else Hx[o-128][n].
// ---------------------------------------------------------------------------
__launch_bounds__(256)
__global__ void proj_mfma(const float* __restrict__ x, const _Float16* __restrict__ Wall,
                          const float* __restrict__ Ball,
                          _Float16* __restrict__ Ft, _Float16* __restrict__ Gt,
                          _Float16* __restrict__ Hx) {
    const int N = NN, C = CC;
    int n0 = blockIdx.x * 128;
    int o0 = blockIdx.y * 128;
    int b  = blockIdx.z;
    const float* xb = x + (size_t)b * C * N;
    __shared__ _Float16 As[128 * 32];   // [o][k]
    __shared__ _Float16 Bs[32 * 128];   // [k][n]
    int tid = threadIdx.x, lane = tid & 63, wave = tid >> 6;
    int wm = wave & 1, wn = wave >> 1, lrow = lane & 15, quad = lane >> 4;
    int bk = tid >> 3;   // 0..31 B-staging row
    int bs = tid & 7;    // 0..7  B-staging 16-col segment
    f32x4 acc[4][4] = {};
    for (int kc = 0; kc < C; kc += 32) {
        __syncthreads();
        stage_tile(Wall + (size_t)o0 * C + kc, C, As, lane, wave);
        const float* xr = xb + (size_t)(kc + bk) * N + n0 + bs * 16;
        float4 v0 = *(const float4*)(xr);
        float4 v1 = *(const float4*)(xr + 4);
        float4 v2 = *(const float4*)(xr + 8);
        float4 v3 = *(const float4*)(xr + 12);
        f16x8 h0 = { (_Float16)v0.x, (_Float16)v0.y, (_Float16)v0.z, (_Float16)v0.w,
                     (_Float16)v1.x, (_Float16)v1.y, (_Float16)v1.z, (_Float16)v1.w };
        f16x8 h1 = { (_Float16)v2.x, (_Float16)v2.y, (_Float16)v2.z, (_Float16)v2.w,
                     (_Float16)v3.x, (_Float16)v3.y, (_Float16)v3.z, (_Float16)v3.w };
        *(f16x8*)(Bs + bk * 128 + bs * 16)     = h0;
        *(f16x8*)(Bs + bk * 128 + bs * 16 + 8) = h1;
        __syncthreads();
        f16x8 af[4], bfr[4];
        #pragma unroll
        for (int mi = 0; mi < 4; mi++)
            af[mi] = *(const f16x8*)(As + (wm * 64 + mi * 16 + lrow) * 32 + quad * 8);
        #pragma unroll
        for (int ni = 0; ni < 4; ni++) {
            int n = wn * 64 + ni * 16 + lrow;
            #pragma unroll
            for (int j = 0; j < 8; j++)
                bfr[ni][j] = Bs[(quad * 8 + j) * 128 + n];
        }
        #pragma unroll
        for (int mi = 0; mi < 4; mi++)
            #pragma unroll
            for (int ni = 0; ni < 4; ni++)
                acc[mi][ni] = __builtin_amdgcn_mfma_f32_16x16x32_f16(af[mi], bfr[ni], acc[mi][ni], 0, 0, 0);
    }
    float bias_r[4][4];
    #pragma unroll
    for (int mi = 0; mi < 4; mi++)
        #pragma unroll
        for (int r = 0; r < 4; r++)
            bias_r[mi][r] = Ball[o0 + wm * 64 + mi * 16 + quad * 4 + r];
    _Float16* Ftb = Ft + (size_t)b * NN * CKK;
    _Float16* Gtb = Gt + (size_t)b * NN * CKK;
    _Float16* Hxb = Hx + (size_t)b * CC * N;
    #pragma unroll
    for (int mi = 0; mi < 4; mi++)
        #pragma unroll
        for (int ni = 0; ni < 4; ni++)
            #pragma unroll
            for (int r = 0; r < 4; r++) {
                int o = o0 + wm * 64 + mi * 16 + quad * 4 + r;
                int n = n0 + wn * 64 + ni * 16 + lrow;
                _Float16 v = (_Float16)(acc[mi][ni][r] + bias_r[mi][r]);
                if (o < 64)       Ftb[(size_t)n * CKK + o] = v;
                else if (o < 128) Gtb[(size_t)n * CKK + (o - 64)] = v;
                else              Hxb[(size_t)(o - 128) * N + n] = v;
            }
}

// ---------------------------------------------------------------------------
// K2: energy MFMA. E[i][j] = sum_k Ft[i][k] * Gt[j][k]  (NT, K=64)
// ---------------------------------------------------------------------------
__launch_bounds__(256)
__global__ void energy_mfma(const _Float16* __restrict__ Ft, const _Float16* __restrict__ Gt,
                            _Float16* __restrict__ E, int r0, int Rstr) {
    const int N = NN;
    int b = blockIdx.z;
    const _Float16* Arow = Ft + (size_t)b * N * CKK + (size_t)(r0 + blockIdx.y * 128) * CKK;
    const _Float16* Brow = Gt + (size_t)b * N * CKK + (size_t)(blockIdx.x * 128) * CKK;
    _Float16* Eb = E + (size_t)b * Rstr * N + (size_t)blockIdx.y * 128 * N + blockIdx.x * 128;
    __shared__ _Float16 As[128 * 32];
    __shared__ _Float16 Bs[128 * 32];
    int tid = threadIdx.x, lane = tid & 63, wave = tid >> 6;
    int wm = wave & 1, wn = wave >> 1, lrow = lane & 15, quad = lane >> 4;
    f32x4 acc[4][4] = {};
    #pragma unroll
    for (int kc = 0; kc < CKK; kc += 32) {
        __syncthreads();
        stage_tile(Arow + kc, CKK, As, lane, wave);
        stage_tile(Brow + kc, CKK, Bs, lane, wave);
        __syncthreads();
        f16x8 af[4], bf[4];
        #pragma unroll
        for (int mi = 0; mi < 4; mi++)
            af[mi] = *(const f16x8*)(As + (wm * 64 + mi * 16 + lrow) * 32 + quad * 8);
        #pragma unroll
        for (int ni = 0; ni < 4; ni++)
            bf[ni] = *(const f16x8*)(Bs + (wn * 64 + ni * 16 + lrow) * 32 + quad * 8);
        #pragma unroll
        for (int mi = 0; mi < 4; mi++)
            #pragma unroll
            for (int ni = 0; ni < 4; ni++)
                acc[mi][ni] = __builtin_amdgcn_mfma_f32_16x16x32_f16(af[mi], bf[ni], acc[mi][ni], 0, 0, 0);
    }
    #pragma unroll
    for (int mi = 0; mi < 4; mi++)
        #pragma unroll
        for (int ni = 0; ni < 4; ni++)
            #pragma unroll
            for (int r = 0; r < 4; r++) {
                int il = wm * 64 + mi * 16 + quad * 4 + r;
                int j  = wn * 64 + ni * 16 + lrow;
                Eb[(size_t)il * N + j] = (_Float16)acc[mi][ni][r];
            }
}

// ---------------------------------------------------------------------------
// K3: in-place f16 row softmax, one block per row.
// ---------------------------------------------------------------------------
__launch_bounds__(256)
__global__ void softmax_f16(_Float16* __restrict__ E, size_t bstride) {
    _Float16* p = E + blockIdx.y * bstride + (size_t)blockIdx.x * NN;
    int tid = threadIdx.x;
    f16x8 v0 = *(const f16x8*)(p + tid * 8);
    f16x8 v1 = *(const f16x8*)(p + 2048 + tid * 8);
    float f[16];
    #pragma unroll
    for (int j = 0; j < 8; j++) { f[j] = (float)v0[j]; f[8 + j] = (float)v1[j]; }
    float m = -1e30f;
    #pragma unroll
    for (int j = 0; j < 16; j++) m = fmaxf(m, f[j]);
    #pragma unroll
    for (int off = 32; off > 0; off >>= 1) m = fmaxf(m, __shfl_down(m, off));
    __shared__ float red[8];
    int wave = tid >> 6, lane = tid & 63;
    if (lane == 0) red[wave] = m;
    __syncthreads();
    m = fmaxf(fmaxf(red[0], red[1]), fmaxf(red[2], red[3]));
    float s = 0.f;
    #pragma unroll
    for (int j = 0; j < 16; j++) { f[j] = __expf(f[j] - m); s += f[j]; }
    #pragma unroll
    for (int off = 32; off > 0; off >>= 1) s += __shfl_down(s, off);
    if (lane == 0) red[4 + wave] = s;
    __syncthreads();
    s = red[4] + red[5] + red[6] + red[7];
    float inv = 1.0f / s;
    #pragma unroll
    for (int j = 0; j < 8; j++) { v0[j] = (_Float16)(f[j] * inv); v1[j] = (_Float16)(f[8 + j] * inv); }
    *(f16x8*)(p + tid * 8) = v0;
    *(f16x8*)(p + 2048 + tid * 8) = v1;
}

// ---------------------------------------------------------------------------
// K4: out MFMA. O[c][i] = sum_j Hx[c][j] * P[i][j]  (NT, K=4096)
// epilogue: out = gamma*O + x (fp32)
// ---------------------------------------------------------------------------
__launch_bounds__(256)
__global__ void out_mfma(const _Float16* __restrict__ Hx, const _Float16* __restrict__ P,
                         const float* __restrict__ x, const float* __restrict__ gamma,
                         float* __restrict__ out, int r0, int Rstr) {
    const int N = NN, C = CC;
    int b = blockIdx.z;
    int i0l = blockIdx.x * 128;
    int c0  = blockIdx.y * 128;
    const _Float16* Arow = Hx + (size_t)b * C * N + (size_t)c0 * N;
    const _Float16* Brow = P  + (size_t)b * Rstr * N + (size_t)i0l * N;
    __shared__ _Float16 As[128 * 32];
    __shared__ _Float16 Bs[128 * 32];
    int tid = threadIdx.x, lane = tid & 63, wave = tid >> 6;
    int wm = wave & 1, wn = wave >> 1, lrow = lane & 15, quad = lane >> 4;
    f32x4 acc[4][4] = {};
    for (int kc = 0; kc < N; kc += 32) {
        __syncthreads();
        stage_tile(Arow + kc, N, As, lane, wave);
        stage_tile(Brow + kc, N, Bs, lane, wave);
        __syncthreads();
        f16x8 af[4], bf[4];
        #pragma unroll
        for (int mi = 0; mi < 4; mi++)
            af[mi] = *(const f16x8*)(As + (wm * 64 + mi * 16 + lrow) * 32 + quad * 8);
        #pragma unroll
        for (int ni = 0; ni < 4; ni++)
            bf[ni] = *(const f16x8*)(Bs + (wn * 64 + ni * 16 + lrow) * 32 + quad * 8);
        #pragma unroll
        for (int mi = 0; mi < 4; mi++)
            #pragma unroll
            for (int ni = 0; ni < 4; ni++)
                acc[mi][ni] = __builtin_amdgcn_mfma_f32_16x16x32_f16(af[mi], bf[ni], acc[mi][ni], 0, 0, 0);
    }
    float gv = gamma[0];
    const float* xb = x + (size_t)b * C * N;
    float* ob = out + (size_t)b * C * N;
    int ig0 = r0 + i0l;
    #pragma unroll
    for (int mi = 0; mi < 4; mi++)
        #pragma unroll
        for (int ni = 0; ni < 4; ni++)
            #pragma unroll
            for (int r = 0; r < 4; r++) {
                int c = c0 + wm * 64 + mi * 16 + quad * 4 + r;
                int i = ig0 + wn * 64 + ni * 16 + lrow;
                ob[(size_t)c * N + i] = gv * acc[mi][ni][r] + xb[(size_t)c * N + i];
            }
}

extern "C" void kernel_launch(void* const* d_in, const int* in_sizes, int n_in,
                              void* d_out, int out_size, void* d_ws, size_t ws_size,
                              hipStream_t stream) {
    const float* x     = (const float*)d_in[0];
    const float* Wf    = (const float*)d_in[1];
    const float* bf    = (const float*)d_in[2];
    const float* Wg    = (const float*)d_in[3];
    const float* bg    = (const float*)d_in[4];
    const float* Wh    = (const float*)d_in[5];
    const float* bh    = (const float*)d_in[6];
    const float* gamma = (const float*)d_in[7];
    float* out = (float*)d_out;

    const int B = NB, C = CC, N = NN;

    // Workspace layout (bytes):
    //   Wall [640][512] f16   @ 0        (640 KiB)
    //   Ball [640]     fp32   @ 768 KiB
    //   Ft [B][N][64]  f16    @ 1 MiB    (2 MiB)
    //   Gt [B][N][64]  f16    @ 3 MiB    (2 MiB)
    //   Hx [B][C][N]   f16    @ 5 MiB    (16 MiB)
    //   E  [B][R][N]   f16    @ 21 MiB   (chunk, auto-sized)
    char* wsb = (char*)d_ws;
    _Float16* Wall = (_Float16*)wsb;
    float*    Ball = (float*)(wsb + ((size_t)768 << 10));
    _Float16* Ft = (_Float16*)(wsb + ((size_t)1 << 20));
    _Float16* Gt = (_Float16*)(wsb + ((size_t)3 << 20));
    _Float16* Hx = (_Float16*)(wsb + ((size_t)5 << 20));
    _Float16* E  = (_Float16*)(wsb + ((size_t)21 << 20));
    size_t base = (size_t)21 << 20;
    size_t avail = (ws_size > base) ? ws_size - base : 0;
    size_t bytesPer128 = (size_t)B * N * 2 * 128;  // 4 MiB per 128 rows
    int R = (int)(avail / bytesPer128) * 128;
    if (R > N) R = N;
    if (R < 128) R = 128;

    convert_w<<<dim3(640), dim3(256), 0, stream>>>(Wf, bf, Wg, bg, Wh, bh, Wall, Ball);
    proj_mfma<<<dim3(N / 128, 5, B), dim3(256), 0, stream>>>(x, Wall, Ball, Ft, Gt, Hx);

    for (int r0 = 0; r0 < N; r0 += R) {
        int rows = (R < N - r0) ? R : (N - r0);
        energy_mfma<<<dim3(N / 128, rows / 128, B), dim3(256), 0, stream>>>(Ft, Gt, E, r0, R);
        softmax_f16<<<dim3(rows, B), dim3(256), 0, stream>>>(E, (size_t)R * N);
        out_mfma<<<dim3(rows / 128, C / 128, B), dim3(256), 0, stream>>>(Hx, E, x, gamma, out, r0, R);
    }
}